// Round 21
// baseline (111.773 us; speedup 1.0000x reference)
//
#include <hip/hip_runtime.h>
#include <math.h>

#define NPIX 4096
#define CIN  512
#define CR   64
#define NB   16

typedef __bf16 bf16x8 __attribute__((ext_vector_type(8)));
typedef float  f32x4  __attribute__((ext_vector_type(4)));
typedef float  f32x16 __attribute__((ext_vector_type(16)));
typedef unsigned int uint;
typedef uint   uint4v __attribute__((ext_vector_type(4)));
typedef unsigned short ushort;
typedef unsigned long long u64;

// workspace layout (BYTE offsets)
static const size_t Q_OFF   = 65536;                               // bf16 [16][64][4096]    8.39 MB
static const size_t QT_OFF  = Q_OFF  + (size_t)NB*CR*NPIX*2;       // qt4 granules           8.39 MB
static const size_t ATT_OFF = QT_OFF + (size_t)NB*NPIX*CR*2;       // f32  [16][64][64]      0.26 MB
static const size_t MB_OFF  = ATT_OFF + (size_t)NB*CR*CR*4;        // bf16 [16][512][64]     1.05 MB
// total ~18.2 MB

// qt4: fragment-native layout. 8-B granule (uint2) = 4 consecutive o's for one px.
// slot(b,px,of,kg,pxlo) = ((((b*256 + (px>>4))*4 + of)*4 + kg)*16 + (px&15)

static __device__ inline uint pk_bf16(float a, float b) {
    uint r;
    asm volatile("v_cvt_pk_bf16_f32 %0, %1, %2" : "=v"(r) : "v"(a), "v"(b));
    return r;   // low 16 = a, high 16 = b
}

// K1 pipeline macros — R16-proven 64-px version.
#define K1_LOAD(XV, WF, KS) do {                                             \
    int k0_ = (KS) * 32 + kg * 8;                                            \
    _Pragma("unroll")                                                        \
    for (int pf = 0; pf < 4; pf++) {                                         \
        const float* xp_ = xb + (size_t)k0_ * NPIX + pf * 16;                \
        _Pragma("unroll")                                                    \
        for (int j = 0; j < 8; j++) XV[pf][j] = xp_[(size_t)j * NPIX];       \
    }                                                                        \
    _Pragma("unroll")                                                        \
    for (int of = 0; of < 4; of++) {                                         \
        const float* wp_ = w1 + (size_t)(of * 16 + lo) * CIN + k0_;          \
        WF[of][0] = *(const f32x4*)wp_;                                      \
        WF[of][1] = *(const f32x4*)(wp_ + 4);                                \
    }                                                                        \
} while (0)

#define K1_COMPUTE(XV, WF) do {                                              \
    bf16x8 af_[4];                                                           \
    _Pragma("unroll")                                                        \
    for (int of = 0; of < 4; of++) {                                         \
        uint4v au_;                                                          \
        au_[0] = pk_bf16(WF[of][0][0], WF[of][0][1]);                        \
        au_[1] = pk_bf16(WF[of][0][2], WF[of][0][3]);                        \
        au_[2] = pk_bf16(WF[of][1][0], WF[of][1][1]);                        \
        au_[3] = pk_bf16(WF[of][1][2], WF[of][1][3]);                        \
        af_[of] = __builtin_bit_cast(bf16x8, au_);                           \
    }                                                                        \
    _Pragma("unroll")                                                        \
    for (int pf = 0; pf < 4; pf++) {                                         \
        uint4v bu_;                                                          \
        _Pragma("unroll")                                                    \
        for (int j = 0; j < 4; j++)                                          \
            bu_[j] = pk_bf16(XV[pf][2 * j], XV[pf][2 * j + 1]);              \
        bf16x8 bf_ = __builtin_bit_cast(bf16x8, bu_);                        \
        _Pragma("unroll")                                                    \
        for (int of = 0; of < 4; of++)                                       \
            acc[pf][of] = __builtin_amdgcn_mfma_f32_16x16x32_bf16(           \
                af_[of], bf_, acc[pf][of], 0, 0, 0);                         \
    }                                                                        \
} while (0)

// K1: q[b][o][n] = sum_c w1[o][c] x[b][c][n] + b1[o]  via MFMA, NO LDS.
// Wave tile 64o x 64px, double-buffered prefetch pipeline. (proven)
__global__ __launch_bounds__(256) void k1_conv1(const float* __restrict__ x,
                                                const float* __restrict__ w1,
                                                const float* __restrict__ b1,
                                                ushort* __restrict__ q,
                                                uint2* __restrict__ qt4) {
    int b = blockIdx.y;
    int t = threadIdx.x;
    int wid = t >> 6, l = t & 63;
    int lo = l & 15, kg = l >> 4;
    int px0 = blockIdx.x * 256 + wid * 64;
    const float* xb = x + (size_t)b * CIN * NPIX + px0 + lo;

    f32x4 acc[4][4] = {};                 // [pf][of]
    float xvA[4][8], xvB[4][8];
    f32x4 wfA[4][2], wfB[4][2];

    K1_LOAD(xvA, wfA, 0);
#pragma unroll
    for (int ks2 = 0; ks2 < 8; ks2++) {
        K1_LOAD(xvB, wfB, 2 * ks2 + 1);
        K1_COMPUTE(xvA, wfA);
        if (ks2 < 7) K1_LOAD(xvA, wfA, 2 * ks2 + 2);
        K1_COMPUTE(xvB, wfB);
    }

    // epilogue: +b1; store q[o][px] (scalar) and qt4 granules (lane-linear)
#pragma unroll
    for (int pf = 0; pf < 4; pf++) {
        int px = px0 + pf * 16 + lo;
        ushort* qb = q + (size_t)b * CR * NPIX + px;
        uint2* qt4b = qt4 + (((size_t)b * 256 + (px0 >> 4) + pf) * 4) * 64 + kg * 16 + lo;
#pragma unroll
        for (int of = 0; of < 4; of++) {
            int o = of * 16 + kg * 4;
            float v0 = acc[pf][of][0] + b1[o + 0];
            float v1 = acc[pf][of][1] + b1[o + 1];
            float v2 = acc[pf][of][2] + b1[o + 2];
            float v3 = acc[pf][of][3] + b1[o + 3];
            uint p0 = pk_bf16(v0, v1), p1 = pk_bf16(v2, v3);
            qb[(size_t)(o + 0) * NPIX] = (ushort)(p0 & 0xffff);
            qb[(size_t)(o + 1) * NPIX] = (ushort)(p0 >> 16);
            qb[(size_t)(o + 2) * NPIX] = (ushort)(p1 & 0xffff);
            qb[(size_t)(o + 3) * NPIX] = (ushort)(p1 >> 16);
            qt4b[of * 64] = make_uint2(p0, p1);
        }
    }
}

// K2: att rows for one (b, c-quarter) per block — proven R18 version.
__global__ __launch_bounds__(512) void k2_att(const ushort* __restrict__ q,
                                              float* __restrict__ att) {
    __shared__ float part[8][16][66];    // 33.8 KB
    int cq = blockIdx.x;                 // c-quarter 0..3
    int b  = blockIdx.y;
    int t = threadIdx.x;
    int w = t >> 6, l = t & 63;
    int lo = l & 15, kg = l >> 4;
    const ushort* qb = q + (size_t)b * CR * NPIX + w * 512;

    f32x4 acc[4] = {};                   // [df]
    for (int ks = 0; ks < 16; ks++) {
        int koff = ks * 32 + kg * 8;
        bf16x8 fa = *(const bf16x8*)(qb + (size_t)(cq * 16 + lo) * NPIX + koff);
        bf16x8 fr[4];
#pragma unroll
        for (int df = 0; df < 4; df++)
            fr[df] = *(const bf16x8*)(qb + (size_t)(df * 16 + lo) * NPIX + koff);
#pragma unroll
        for (int df = 0; df < 4; df++)
            acc[df] = __builtin_amdgcn_mfma_f32_16x16x32_bf16(fa, fr[df], acc[df], 0, 0, 0);
    }
#pragma unroll
    for (int df = 0; df < 4; df++)
#pragma unroll
        for (int r = 0; r < 4; r++)
            part[w][kg * 4 + r][df * 16 + lo] = acc[df][r];
    __syncthreads();

    // reduce 8 wave-partials + softmax; 2 rows per wave
#pragma unroll
    for (int i = 0; i < 2; i++) {
        int cl = w * 2 + i;
        float v = 0.f;
#pragma unroll
        for (int pw = 0; pw < 8; pw++) v += part[pw][cl][l];
        float m = v;
#pragma unroll
        for (int s = 1; s < 64; s <<= 1) m = fmaxf(m, __shfl_xor(m, s, 64));
        float e = __expf(v - m);
        float ssum = e;
#pragma unroll
        for (int s = 1; s < 64; s <<= 1) ssum += __shfl_xor(ssum, s, 64);
        att[((size_t)b * CR + cq * 16 + cl) * CR + l] = e / ssum;
    }
}

// K3: mb[b][c][d] = bf16( sum_k w2[c][k] att[b][k][d] )
// Widened to 256 blocks (dg eighths, acc[8]) — was 128 blocks = half the CUs.
__global__ __launch_bounds__(256) void k3_m(const float* __restrict__ w2,
                                            const float* __restrict__ att,
                                            ushort* __restrict__ mb) {
    int b = blockIdx.y;
    int c  = (blockIdx.x >> 3) * 256 + threadIdx.x;  // 0..511
    int dg = (blockIdx.x & 7) * 8;
    const float* ab  = att + (size_t)b * CR * CR + dg;
    const float* w2r = w2 + (size_t)c * CR;
    float acc[8];
#pragma unroll
    for (int j = 0; j < 8; j++) acc[j] = 0.f;
    for (int k = 0; k < CR; k++) {
        float wv = w2r[k];
#pragma unroll
        for (int j4 = 0; j4 < 2; j4++) {
            f32x4 av = *(const f32x4*)(ab + k * CR + j4 * 4);
#pragma unroll
            for (int u = 0; u < 4; u++)
                acc[j4 * 4 + u] = fmaf(wv, av[u], acc[j4 * 4 + u]);
        }
    }
    uint* mp = (uint*)(mb + ((size_t)b * CIN + c) * CR + dg);
#pragma unroll
    for (int i = 0; i < 4; i++)
        mp[i] = pk_bf16(acc[2 * i], acc[2 * i + 1]);
}

// K4: y[b][c][n] = sum_d mb[c][d] qt[n][d] + b2[c] + x[b][c][n]
// 32x32x16 MFMA, all 16 cc tiles inside, software-pipelined. (proven)
// y: NONTEMPORAL stores (R19-proven, keeps x in L3).
// x and qt4 are LAST-USE reads -> nontemporal LOADS (qt4 loaded as u64
// scalars — the builtin rejects HIP_vector_type pointers).
#define K4_LOAD(AF, XR, CC) do {                                             \
    int c0_ = (CC) * 32;                                                     \
    const ushort* mrow_ = mb + ((size_t)b * CIN + c0_ + l31) * CR;           \
    _Pragma("unroll")                                                        \
    for (int ks = 0; ks < 4; ks++)                                           \
        AF[ks] = *(const bf16x8*)(mrow_ + ks * 16 + lhi * 8);                \
    _Pragma("unroll")                                                        \
    for (int r = 0; r < 16; r++) {                                           \
        int rowD_ = (r & 3) + 8 * (r >> 2) + 4 * lhi;                        \
        XR[r] = __builtin_nontemporal_load(                                  \
            x + ((size_t)b * CIN + c0_ + rowD_) * NPIX + px);                \
    }                                                                        \
} while (0)

#define K4_STORE(AF, XR, CC) do {                                            \
    int c0_ = (CC) * 32;                                                     \
    f32x16 acc_ = {};                                                        \
    _Pragma("unroll")                                                        \
    for (int ks = 0; ks < 4; ks++)                                           \
        acc_ = __builtin_amdgcn_mfma_f32_32x32x16_bf16(AF[ks], bf[ks], acc_, 0, 0, 0); \
    _Pragma("unroll")                                                        \
    for (int r = 0; r < 16; r++) {                                           \
        int rowD_ = (r & 3) + 8 * (r >> 2) + 4 * lhi;                        \
        int c_ = c0_ + rowD_;                                                \
        size_t off_ = ((size_t)b * CIN + c_) * NPIX + px;                    \
        __builtin_nontemporal_store(acc_[r] + b2[c_] + XR[r], y + off_);     \
    }                                                                        \
} while (0)

__global__ __launch_bounds__(256) void k4_out(const uint2* __restrict__ qt4,
                                              const ushort* __restrict__ mb,
                                              const float* __restrict__ b2,
                                              const float* __restrict__ x,
                                              float* __restrict__ y) {
    int b = blockIdx.y;
    int t = threadIdx.x;
    int wid = t >> 6, l = t & 63;
    int l31 = l & 31, lhi = l >> 5;
    int pxblk = blockIdx.x * 128 + wid * 32;
    int px = pxblk + l31;
    const u64* qt4b = (const u64*)(qt4 + (size_t)b * 65536);
    int pxhi = (pxblk >> 4) + ((l >> 4) & 1);
    int pxlo = l & 15;
    int kg2 = lhi * 2;

    // qt B-frags: load ONCE for all 16 cc tiles (last use -> nontemporal u64)
    bf16x8 bf[4];
#pragma unroll
    for (int ks = 0; ks < 4; ks++) {
        const u64* p_ = qt4b + (((size_t)pxhi * 4 + ks) * 4 + kg2) * 16 + pxlo;
        u64 g0 = __builtin_nontemporal_load(p_);
        u64 g1 = __builtin_nontemporal_load(p_ + 16);
        uint4v u;
        u[0] = (uint)g0; u[1] = (uint)(g0 >> 32);
        u[2] = (uint)g1; u[3] = (uint)(g1 >> 32);
        bf[ks] = __builtin_bit_cast(bf16x8, u);
    }

    bf16x8 afA[4], afB[4];
    float xrA[16], xrB[16];
    K4_LOAD(afA, xrA, 0);
#pragma unroll
    for (int i2 = 0; i2 < 8; i2++) {
        K4_LOAD(afB, xrB, 2 * i2 + 1);
        K4_STORE(afA, xrA, 2 * i2);
        if (i2 < 7) K4_LOAD(afA, xrA, 2 * i2 + 2);
        K4_STORE(afB, xrB, 2 * i2 + 1);
    }
}

extern "C" void kernel_launch(void* const* d_in, const int* in_sizes, int n_in,
                              void* d_out, int out_size, void* d_ws, size_t ws_size,
                              hipStream_t stream) {
    const float* x  = (const float*)d_in[0];
    const float* w1 = (const float*)d_in[1];
    const float* b1 = (const float*)d_in[2];
    const float* w2 = (const float*)d_in[3];
    const float* b2 = (const float*)d_in[4];
    float* y = (float*)d_out;
    char* ws = (char*)d_ws;

    ushort* q   = (ushort*)(ws + Q_OFF);
    uint2*  qt4 = (uint2*) (ws + QT_OFF);
    float*  att = (float*) (ws + ATT_OFF);
    ushort* mb  = (ushort*)(ws + MB_OFF);

    hipLaunchKernelGGL(k1_conv1, dim3(16, 16),  dim3(256), 0, stream, x, w1, b1, q, qt4);
    hipLaunchKernelGGL(k2_att,   dim3(4, 16),   dim3(512), 0, stream, q, att);
    hipLaunchKernelGGL(k3_m,     dim3(16, 16),  dim3(256), 0, stream, w2, att, mb);
    hipLaunchKernelGGL(k4_out,   dim3(32, 16),  dim3(256), 0, stream, qt4, mb, b2, x, y);
}

// Round 22
// 106.462 us; speedup vs baseline: 1.0499x; 1.0499x over previous
//
#include <hip/hip_runtime.h>
#include <math.h>

#define NPIX 4096
#define CIN  512
#define CR   64
#define NB   16

typedef __bf16 bf16x8 __attribute__((ext_vector_type(8)));
typedef float  f32x4  __attribute__((ext_vector_type(4)));
typedef float  f32x16 __attribute__((ext_vector_type(16)));
typedef unsigned int uint;
typedef uint   uint4v __attribute__((ext_vector_type(4)));
typedef unsigned short ushort;

// workspace layout (BYTE offsets)
static const size_t Q_OFF   = 65536;                               // bf16 [16][64][4096]    8.39 MB
static const size_t QT_OFF  = Q_OFF  + (size_t)NB*CR*NPIX*2;       // qt4 granules           8.39 MB
static const size_t ATT_OFF = QT_OFF + (size_t)NB*NPIX*CR*2;       // f32  [16][64][64]      0.26 MB
static const size_t MB_OFF  = ATT_OFF + (size_t)NB*CR*CR*4;        // bf16 [16][512][64]     1.05 MB
// total ~18.2 MB

// qt4: fragment-native layout. 8-B granule (uint2) = 4 consecutive o's for one px.
// slot(b,px,of,kg,pxlo) = ((((b*256 + (px>>4))*4 + of)*4 + kg)*16 + (px&15)

static __device__ inline uint pk_bf16(float a, float b) {
    uint r;
    asm volatile("v_cvt_pk_bf16_f32 %0, %1, %2" : "=v"(r) : "v"(a), "v"(b));
    return r;   // low 16 = a, high 16 = b
}

// K1 pipeline macros — R16-proven 64-px version.
#define K1_LOAD(XV, WF, KS) do {                                             \
    int k0_ = (KS) * 32 + kg * 8;                                            \
    _Pragma("unroll")                                                        \
    for (int pf = 0; pf < 4; pf++) {                                         \
        const float* xp_ = xb + (size_t)k0_ * NPIX + pf * 16;                \
        _Pragma("unroll")                                                    \
        for (int j = 0; j < 8; j++) XV[pf][j] = xp_[(size_t)j * NPIX];       \
    }                                                                        \
    _Pragma("unroll")                                                        \
    for (int of = 0; of < 4; of++) {                                         \
        const float* wp_ = w1 + (size_t)(of * 16 + lo) * CIN + k0_;          \
        WF[of][0] = *(const f32x4*)wp_;                                      \
        WF[of][1] = *(const f32x4*)(wp_ + 4);                                \
    }                                                                        \
} while (0)

#define K1_COMPUTE(XV, WF) do {                                              \
    bf16x8 af_[4];                                                           \
    _Pragma("unroll")                                                        \
    for (int of = 0; of < 4; of++) {                                         \
        uint4v au_;                                                          \
        au_[0] = pk_bf16(WF[of][0][0], WF[of][0][1]);                        \
        au_[1] = pk_bf16(WF[of][0][2], WF[of][0][3]);                        \
        au_[2] = pk_bf16(WF[of][1][0], WF[of][1][1]);                        \
        au_[3] = pk_bf16(WF[of][1][2], WF[of][1][3]);                        \
        af_[of] = __builtin_bit_cast(bf16x8, au_);                           \
    }                                                                        \
    _Pragma("unroll")                                                        \
    for (int pf = 0; pf < 4; pf++) {                                         \
        uint4v bu_;                                                          \
        _Pragma("unroll")                                                    \
        for (int j = 0; j < 4; j++)                                          \
            bu_[j] = pk_bf16(XV[pf][2 * j], XV[pf][2 * j + 1]);              \
        bf16x8 bf_ = __builtin_bit_cast(bf16x8, bu_);                        \
        _Pragma("unroll")                                                    \
        for (int of = 0; of < 4; of++)                                       \
            acc[pf][of] = __builtin_amdgcn_mfma_f32_16x16x32_bf16(           \
                af_[of], bf_, acc[pf][of], 0, 0, 0);                         \
    }                                                                        \
} while (0)

// K1: q[b][o][n] = sum_c w1[o][c] x[b][c][n] + b1[o]  via MFMA, NO LDS.
// Wave tile 64o x 64px, double-buffered prefetch pipeline. (proven)
__global__ __launch_bounds__(256) void k1_conv1(const float* __restrict__ x,
                                                const float* __restrict__ w1,
                                                const float* __restrict__ b1,
                                                ushort* __restrict__ q,
                                                uint2* __restrict__ qt4) {
    int b = blockIdx.y;
    int t = threadIdx.x;
    int wid = t >> 6, l = t & 63;
    int lo = l & 15, kg = l >> 4;
    int px0 = blockIdx.x * 256 + wid * 64;
    const float* xb = x + (size_t)b * CIN * NPIX + px0 + lo;

    f32x4 acc[4][4] = {};                 // [pf][of]
    float xvA[4][8], xvB[4][8];
    f32x4 wfA[4][2], wfB[4][2];

    K1_LOAD(xvA, wfA, 0);
#pragma unroll
    for (int ks2 = 0; ks2 < 8; ks2++) {
        K1_LOAD(xvB, wfB, 2 * ks2 + 1);
        K1_COMPUTE(xvA, wfA);
        if (ks2 < 7) K1_LOAD(xvA, wfA, 2 * ks2 + 2);
        K1_COMPUTE(xvB, wfB);
    }

    // epilogue: +b1; store q[o][px] (scalar) and qt4 granules (lane-linear)
#pragma unroll
    for (int pf = 0; pf < 4; pf++) {
        int px = px0 + pf * 16 + lo;
        ushort* qb = q + (size_t)b * CR * NPIX + px;
        uint2* qt4b = qt4 + (((size_t)b * 256 + (px0 >> 4) + pf) * 4) * 64 + kg * 16 + lo;
#pragma unroll
        for (int of = 0; of < 4; of++) {
            int o = of * 16 + kg * 4;
            float v0 = acc[pf][of][0] + b1[o + 0];
            float v1 = acc[pf][of][1] + b1[o + 1];
            float v2 = acc[pf][of][2] + b1[o + 2];
            float v3 = acc[pf][of][3] + b1[o + 3];
            uint p0 = pk_bf16(v0, v1), p1 = pk_bf16(v2, v3);
            qb[(size_t)(o + 0) * NPIX] = (ushort)(p0 & 0xffff);
            qb[(size_t)(o + 1) * NPIX] = (ushort)(p0 >> 16);
            qb[(size_t)(o + 2) * NPIX] = (ushort)(p1 & 0xffff);
            qb[(size_t)(o + 3) * NPIX] = (ushort)(p1 >> 16);
            qt4b[of * 64] = make_uint2(p0, p1);
        }
    }
}

// K2: att rows for one (b, c-quarter) per block — proven R18 version.
__global__ __launch_bounds__(512) void k2_att(const ushort* __restrict__ q,
                                              float* __restrict__ att) {
    __shared__ float part[8][16][66];    // 33.8 KB
    int cq = blockIdx.x;                 // c-quarter 0..3
    int b  = blockIdx.y;
    int t = threadIdx.x;
    int w = t >> 6, l = t & 63;
    int lo = l & 15, kg = l >> 4;
    const ushort* qb = q + (size_t)b * CR * NPIX + w * 512;

    f32x4 acc[4] = {};                   // [df]
    for (int ks = 0; ks < 16; ks++) {
        int koff = ks * 32 + kg * 8;
        bf16x8 fa = *(const bf16x8*)(qb + (size_t)(cq * 16 + lo) * NPIX + koff);
        bf16x8 fr[4];
#pragma unroll
        for (int df = 0; df < 4; df++)
            fr[df] = *(const bf16x8*)(qb + (size_t)(df * 16 + lo) * NPIX + koff);
#pragma unroll
        for (int df = 0; df < 4; df++)
            acc[df] = __builtin_amdgcn_mfma_f32_16x16x32_bf16(fa, fr[df], acc[df], 0, 0, 0);
    }
#pragma unroll
    for (int df = 0; df < 4; df++)
#pragma unroll
        for (int r = 0; r < 4; r++)
            part[w][kg * 4 + r][df * 16 + lo] = acc[df][r];
    __syncthreads();

    // reduce 8 wave-partials + softmax; 2 rows per wave
#pragma unroll
    for (int i = 0; i < 2; i++) {
        int cl = w * 2 + i;
        float v = 0.f;
#pragma unroll
        for (int pw = 0; pw < 8; pw++) v += part[pw][cl][l];
        float m = v;
#pragma unroll
        for (int s = 1; s < 64; s <<= 1) m = fmaxf(m, __shfl_xor(m, s, 64));
        float e = __expf(v - m);
        float ssum = e;
#pragma unroll
        for (int s = 1; s < 64; s <<= 1) ssum += __shfl_xor(ssum, s, 64);
        att[((size_t)b * CR + cq * 16 + cl) * CR + l] = e / ssum;
    }
}

// K3: mb[b][c][d] = bf16( sum_k w2[c][k] att[b][k][d] )
// 256 blocks (dg eighths, acc[8]) — kept from R21 (mechanistically neutral+).
__global__ __launch_bounds__(256) void k3_m(const float* __restrict__ w2,
                                            const float* __restrict__ att,
                                            ushort* __restrict__ mb) {
    int b = blockIdx.y;
    int c  = (blockIdx.x >> 3) * 256 + threadIdx.x;  // 0..511
    int dg = (blockIdx.x & 7) * 8;
    const float* ab  = att + (size_t)b * CR * CR + dg;
    const float* w2r = w2 + (size_t)c * CR;
    float acc[8];
#pragma unroll
    for (int j = 0; j < 8; j++) acc[j] = 0.f;
    for (int k = 0; k < CR; k++) {
        float wv = w2r[k];
#pragma unroll
        for (int j4 = 0; j4 < 2; j4++) {
            f32x4 av = *(const f32x4*)(ab + k * CR + j4 * 4);
#pragma unroll
            for (int u = 0; u < 4; u++)
                acc[j4 * 4 + u] = fmaf(wv, av[u], acc[j4 * 4 + u]);
        }
    }
    uint* mp = (uint*)(mb + ((size_t)b * CIN + c) * CR + dg);
#pragma unroll
    for (int i = 0; i < 4; i++)
        mp[i] = pk_bf16(acc[2 * i], acc[2 * i + 1]);
}

// K4: y[b][c][n] = sum_d mb[c][d] qt[n][d] + b2[c] + x[b][c][n]
// 32x32x16 MFMA, all 16 cc tiles inside, software-pipelined. (proven)
// y: NONTEMPORAL stores ONLY (R19-proven: keeps x resident in L3 for k4's
// re-read). NT *loads* reverted — R21 showed they bypass the L3 benefit
// (−3.6 µs): plain loads for x and qt4.
#define K4_LOAD(AF, XR, CC) do {                                             \
    int c0_ = (CC) * 32;                                                     \
    const ushort* mrow_ = mb + ((size_t)b * CIN + c0_ + l31) * CR;           \
    _Pragma("unroll")                                                        \
    for (int ks = 0; ks < 4; ks++)                                           \
        AF[ks] = *(const bf16x8*)(mrow_ + ks * 16 + lhi * 8);                \
    _Pragma("unroll")                                                        \
    for (int r = 0; r < 16; r++) {                                           \
        int rowD_ = (r & 3) + 8 * (r >> 2) + 4 * lhi;                        \
        XR[r] = x[((size_t)b * CIN + c0_ + rowD_) * NPIX + px];              \
    }                                                                        \
} while (0)

#define K4_STORE(AF, XR, CC) do {                                            \
    int c0_ = (CC) * 32;                                                     \
    f32x16 acc_ = {};                                                        \
    _Pragma("unroll")                                                        \
    for (int ks = 0; ks < 4; ks++)                                           \
        acc_ = __builtin_amdgcn_mfma_f32_32x32x16_bf16(AF[ks], bf[ks], acc_, 0, 0, 0); \
    _Pragma("unroll")                                                        \
    for (int r = 0; r < 16; r++) {                                           \
        int rowD_ = (r & 3) + 8 * (r >> 2) + 4 * lhi;                        \
        int c_ = c0_ + rowD_;                                                \
        size_t off_ = ((size_t)b * CIN + c_) * NPIX + px;                    \
        __builtin_nontemporal_store(acc_[r] + b2[c_] + XR[r], y + off_);     \
    }                                                                        \
} while (0)

__global__ __launch_bounds__(256) void k4_out(const uint2* __restrict__ qt4,
                                              const ushort* __restrict__ mb,
                                              const float* __restrict__ b2,
                                              const float* __restrict__ x,
                                              float* __restrict__ y) {
    int b = blockIdx.y;
    int t = threadIdx.x;
    int wid = t >> 6, l = t & 63;
    int l31 = l & 31, lhi = l >> 5;
    int pxblk = blockIdx.x * 128 + wid * 32;
    int px = pxblk + l31;
    const uint2* qt4b = qt4 + (size_t)b * 65536;
    int pxhi = (pxblk >> 4) + ((l >> 4) & 1);
    int pxlo = l & 15;
    int kg2 = lhi * 2;

    // qt B-frags: load ONCE for all 16 cc tiles
    bf16x8 bf[4];
#pragma unroll
    for (int ks = 0; ks < 4; ks++) {
        const uint2* p_ = qt4b + (((size_t)pxhi * 4 + ks) * 4 + kg2) * 16 + pxlo;
        uint2 g0 = p_[0], g1 = p_[16];
        uint4v u; u[0] = g0.x; u[1] = g0.y; u[2] = g1.x; u[3] = g1.y;
        bf[ks] = __builtin_bit_cast(bf16x8, u);
    }

    bf16x8 afA[4], afB[4];
    float xrA[16], xrB[16];
    K4_LOAD(afA, xrA, 0);
#pragma unroll
    for (int i2 = 0; i2 < 8; i2++) {
        K4_LOAD(afB, xrB, 2 * i2 + 1);
        K4_STORE(afA, xrA, 2 * i2);
        if (i2 < 7) K4_LOAD(afA, xrA, 2 * i2 + 2);
        K4_STORE(afB, xrB, 2 * i2 + 1);
    }
}

extern "C" void kernel_launch(void* const* d_in, const int* in_sizes, int n_in,
                              void* d_out, int out_size, void* d_ws, size_t ws_size,
                              hipStream_t stream) {
    const float* x  = (const float*)d_in[0];
    const float* w1 = (const float*)d_in[1];
    const float* b1 = (const float*)d_in[2];
    const float* w2 = (const float*)d_in[3];
    const float* b2 = (const float*)d_in[4];
    float* y = (float*)d_out;
    char* ws = (char*)d_ws;

    ushort* q   = (ushort*)(ws + Q_OFF);
    uint2*  qt4 = (uint2*) (ws + QT_OFF);
    float*  att = (float*) (ws + ATT_OFF);
    ushort* mb  = (ushort*)(ws + MB_OFF);

    hipLaunchKernelGGL(k1_conv1, dim3(16, 16),  dim3(256), 0, stream, x, w1, b1, q, qt4);
    hipLaunchKernelGGL(k2_att,   dim3(4, 16),   dim3(512), 0, stream, q, att);
    hipLaunchKernelGGL(k3_m,     dim3(16, 16),  dim3(256), 0, stream, w2, att, mb);
    hipLaunchKernelGGL(k4_out,   dim3(32, 16),  dim3(256), 0, stream, qt4, mb, b2, x, y);
}